// Round 10
// baseline (217.295 us; speedup 1.0000x reference)
//
#include <hip/hip_runtime.h>
#include <hip/hip_bf16.h>
#include <stdint.h>

// Problem constants
#define BATCH 2
#define TT 2048
#define DM 768
#define RR 4
#define M_TOK 4096          // B*T tokens
#define NFEAT 6144          // D*R*2
#define NCH 6144            // B*D*R channels
#define CHUNK 64            // scan chunk length
#define NCHUNK 32           // T / CHUNK

typedef __attribute__((ext_vector_type(8))) short short8;
typedef __attribute__((ext_vector_type(4))) float float4v;

// ---------- helpers ----------
__device__ inline float bf2f(uint32_t bits16) {
    union { uint32_t u; float f; } x; x.u = bits16 << 16; return x.f;
}

typedef const __attribute__((address_space(1))) void* gptr_t;
typedef __attribute__((address_space(3))) void* lptr_t;

__device__ inline void async_ld16(const void* g, void* l) {
    __builtin_amdgcn_global_load_lds((gptr_t)(uintptr_t)g, (lptr_t)(uintptr_t)l,
                                     16, 0, 0);
}

__device__ inline void store_c(__hip_bfloat16* C, size_t idx, float v) {
    C[idx] = __float2bfloat16(v);
}
__device__ inline void store_c(float* C, size_t idx, float v) { C[idx] = v; }

__device__ inline uint2 pack4bf(float a, float b, float c, float d) {
    union { __hip_bfloat16 h[4]; uint2 u; } o;
    o.h[0] = __float2bfloat16(a); o.h[1] = __float2bfloat16(b);
    o.h[2] = __float2bfloat16(c); o.h[3] = __float2bfloat16(d);
    return o.u;
}

__device__ inline float2 cmul(float2 a, float2 b) {
    return make_float2(a.x * b.x - a.y * b.y, a.x * b.y + a.y * b.x);
}

// ---------- complex recurrence step: s = a*s + b*u ----------
__device__ inline void cstep(float& sr, float& si, float2 a, float2 bb,
                             uint32_t uw) {
    float ur = bf2f(uw & 0xffffu), ui = bf2f(uw >> 16);
    float tr = bb.x * ur - bb.y * ui;
    float ti = bb.x * ui + bb.y * ur;
    float nr = a.x * sr - a.y * si + tr;
    float ni = a.x * si + a.y * sr + ti;
    sr = nr; si = ni;
}

// ---------- fused prep + rmsnorm: block-role split ----------
__global__ __launch_bounds__(256) void prep_rms(
    const float* __restrict__ x, const float* __restrict__ w,
    const float* __restrict__ W_in, const float* __restrict__ W_out,
    const float* __restrict__ ap, const float* __restrict__ bp,
    const float* __restrict__ cp,
    __hip_bfloat16* __restrict__ xn,
    __hip_bfloat16* __restrict__ Win_bf, __hip_bfloat16* __restrict__ Wout_bf,
    float2* __restrict__ ac, float2* __restrict__ bc,
    float2* __restrict__ cc, float2* __restrict__ aL) {
    int bid = blockIdx.x;
    int tid = threadIdx.x;
    if (bid < M_TOK) {
        // ---- RMSNorm for token `bid` ----
        __shared__ float wsum[3];
        float4 v = make_float4(0.f, 0.f, 0.f, 0.f);
        if (tid < 192) v = ((const float4*)(x + (size_t)bid * DM))[tid];
        float ss = v.x * v.x + v.y * v.y + v.z * v.z + v.w * v.w;
        #pragma unroll
        for (int o = 1; o < 64; o <<= 1) ss += __shfl_xor(ss, o);
        if (tid < 192 && (tid & 63) == 0) wsum[tid >> 6] = ss;
        __syncthreads();
        if (tid < 192) {
            float tot = wsum[0] + wsum[1] + wsum[2];
            float scale = rsqrtf(tot * (1.f / DM) + 1e-6f);
            float4 wv = ((const float4*)w)[tid];
            ((uint2*)(xn + (size_t)bid * DM))[tid] =
                pack4bf(v.x * scale * wv.x, v.y * scale * wv.y,
                        v.z * scale * wv.z, v.w * scale * wv.w);
        }
        return;
    }
    const int N1 = NFEAT * DM / 4;   // float4 count
    const int N2 = DM * DM / 4;
    int i = (bid - M_TOK) * 256 + tid;
    if (i < N1) {
        float4 v = ((const float4*)W_in)[i];
        ((uint2*)Win_bf)[i] = pack4bf(v.x, v.y, v.z, v.w);
    } else if (i < N1 + N2) {
        int k = i - N1;
        float4 v = ((const float4*)W_out)[k];
        ((uint2*)Wout_bf)[k] = pack4bf(v.x, v.y, v.z, v.w);
    }
    if (i < DM * RR) {
        float ar = tanhf(ap[2 * i])     * 0.97f;
        float ai = tanhf(ap[2 * i + 1]) * 0.97f;
        ac[i] = make_float2(ar, ai);
        bc[i] = make_float2(tanhf(bp[2 * i]), tanhf(bp[2 * i + 1]));
        cc[i] = make_float2(tanhf(cp[2 * i]), tanhf(cp[2 * i + 1]));
        float xr = ar, xi = ai;   // a^CHUNK via 6 squarings
        #pragma unroll
        for (int k = 0; k < 6; ++k) {
            float nr = xr * xr - xi * xi;
            float ni = 2.f * xr * xi;
            xr = nr; xi = ni;
        }
        aL[i] = make_float2(xr, xi);
    }
}

// ---------- GEMM body: C[M,*] = A[M,K] * B[N,K]^T  (bf16 in, OutT out) -----
// BM x BN block tile, BK-deep LDS stage, 4 waves in 2x2, 16x16x32 bf16 MFMA,
// global_load_lds width 16, XOR-swizzled LDS (16B chunks, ^= row & (CPR-1)).
template <int BM, int BN, int BK, typename OutT>
__device__ inline void gemm_body(
    const __hip_bfloat16* __restrict__ A, const __hip_bfloat16* __restrict__ B,
    OutT* __restrict__ C, int K, int ldc) {
    constexpr int MI = BM / 32;
    constexpr int NJ = BN / 32;
    constexpr int CPR = BK / 8;           // 16B chunks per row
    __shared__ __attribute__((aligned(16))) __hip_bfloat16 lA[BM * BK];
    __shared__ __attribute__((aligned(16))) __hip_bfloat16 lB[BN * BK];
    const int tid  = threadIdx.x;
    const int lane = tid & 63;
    const int wave = tid >> 6;
    const int quad = lane >> 4;
    const int l15  = lane & 15;
    const int wm = (wave >> 1) * (BM / 2);
    const int wn = (wave & 1) * (BN / 2);
    const int m0 = blockIdx.y * BM;
    const int n0 = blockIdx.x * BN;

    float4v acc[MI][NJ] = {};

    for (int k0 = 0; k0 < K; k0 += BK) {
        __syncthreads();
        #pragma unroll
        for (int it = 0; it < BM * CPR / 256; ++it) {
            int p = it * 256 + tid;
            int row = p / CPR;
            int cg = (p & (CPR - 1)) ^ (row & (CPR - 1));
            async_ld16(A + (size_t)(m0 + row) * K + k0 + cg * 8, lA + p * 8);
        }
        #pragma unroll
        for (int it = 0; it < BN * CPR / 256; ++it) {
            int p = it * 256 + tid;
            int row = p / CPR;
            int cg = (p & (CPR - 1)) ^ (row & (CPR - 1));
            async_ld16(B + (size_t)(n0 + row) * K + k0 + cg * 8, lB + p * 8);
        }
        __syncthreads();
        #pragma unroll
        for (int s = 0; s < BK / 32; ++s) {
            short8 af[MI], bfr[NJ];
            #pragma unroll
            for (int i = 0; i < MI; ++i) {
                int r = wm + i * 16 + l15;
                int c = (s * 4 + quad) ^ (r & (CPR - 1));
                af[i] = *(const short8*)(lA + r * BK + c * 8);
            }
            #pragma unroll
            for (int j = 0; j < NJ; ++j) {
                int r = wn + j * 16 + l15;
                int c = (s * 4 + quad) ^ (r & (CPR - 1));
                bfr[j] = *(const short8*)(lB + r * BK + c * 8);
            }
            #pragma unroll
            for (int i = 0; i < MI; ++i)
                #pragma unroll
                for (int j = 0; j < NJ; ++j)
                    acc[i][j] = __builtin_amdgcn_mfma_f32_16x16x32_bf16(
                        af[i], bfr[j], acc[i][j], 0, 0, 0);
        }
    }
    // epilogue: C/D layout col = lane&15, row = quad*4 + reg (m89-verified)
    #pragma unroll
    for (int i = 0; i < MI; ++i)
        #pragma unroll
        for (int j = 0; j < NJ; ++j)
            #pragma unroll
            for (int rg = 0; rg < 4; ++rg) {
                int row = m0 + wm + i * 16 + quad * 4 + rg;
                int col = n0 + wn + j * 16 + l15;
                store_c(C, (size_t)row * ldc + col, acc[i][j][rg]);
            }
}

// in_proj GEMM: 256x128 tile (MI=8, NJ=4) — 2x MFMA per barrier vs 128x128.
__global__ __launch_bounds__(256) void gemm_in_bigm(
    const __hip_bfloat16* __restrict__ A, const __hip_bfloat16* __restrict__ B,
    __hip_bfloat16* __restrict__ C, int K) {
    gemm_body<256, 128, 64, __hip_bfloat16>(A, B, C, K, NFEAT);
}

__global__ __launch_bounds__(256) void gemm_out(
    const __hip_bfloat16* __restrict__ A, const __hip_bfloat16* __restrict__ B,
    float* __restrict__ C, int K) {
    gemm_body<64, 64, 128, float>(A, B, C, K, DM);
}

// ---------- scan_local: chunk-local scans; emit y_local (f32) + chunkEnd ---
// One thread per (batch,d): 4 channels via uint4; u read ONCE.
__global__ __launch_bounds__(256) void scan_local(
    const uint4* __restrict__ u4,              // [(b*T+t)*768 + d]
    const float2* __restrict__ ac, const float2* __restrict__ bc,
    const float2* __restrict__ cc,
    float* __restrict__ y_local,               // [M_TOK][DM] f32
    float2* __restrict__ chunkEnd) {           // [NCHUNK][NCH]
    int g = blockIdx.x * 256 + threadIdx.x;    // 0..1535
    int j = blockIdx.y;
    int b = g >= DM;
    int d = g - b * DM;
    int cb = d * RR;
    float2 a0 = ac[cb], a1 = ac[cb + 1], a2 = ac[cb + 2], a3 = ac[cb + 3];
    float2 b0 = bc[cb], b1 = bc[cb + 1], b2 = bc[cb + 2], b3 = bc[cb + 3];
    float2 c0 = cc[cb], c1 = cc[cb + 1], c2 = cc[cb + 2], c3 = cc[cb + 3];
    float s0r = 0, s0i = 0, s1r = 0, s1i = 0;
    float s2r = 0, s2i = 0, s3r = 0, s3i = 0;
    size_t base = ((size_t)(b * TT + j * CHUNK)) * DM + d;
    #pragma unroll 4
    for (int i = 0; i < CHUNK; ++i) {
        uint4 uw = u4[base + (size_t)i * DM];
        cstep(s0r, s0i, a0, b0, uw.x);
        cstep(s1r, s1i, a1, b1, uw.y);
        cstep(s2r, s2i, a2, b2, uw.z);
        cstep(s3r, s3i, a3, b3, uw.w);
        float yv = c0.x * s0r - c0.y * s0i + c1.x * s1r - c1.y * s1i
                 + c2.x * s2r - c2.y * s2i + c3.x * s3r - c3.y * s3i;
        y_local[base + (size_t)i * DM] = yv;
    }
    size_t eb = (size_t)j * NCH + b * (DM * RR) + cb;
    chunkEnd[eb]     = make_float2(s0r, s0i);
    chunkEnd[eb + 1] = make_float2(s1r, s1i);
    chunkEnd[eb + 2] = make_float2(s2r, s2i);
    chunkEnd[eb + 3] = make_float2(s3r, s3i);
}

// ---------- scan_fix: carry combine + closed-form correction ----------
// y[t][d] = y_local[t][d] + sum_r Re( c_r * a_r^(i+1) * carry_r )
__global__ __launch_bounds__(256) void scan_fix(
    const float* __restrict__ y_local,
    const float2* __restrict__ ac, const float2* __restrict__ cc,
    const float2* __restrict__ aLp, const float2* __restrict__ chunkEnd,
    __hip_bfloat16* __restrict__ y) {          // [B*T*D]
    int g = blockIdx.x * 256 + threadIdx.x;    // 0..1535
    int j = blockIdx.y;
    int b = g >= DM;
    int d = g - b * DM;
    int cb = d * RR;
    float2 a0 = ac[cb], a1 = ac[cb + 1], a2 = ac[cb + 2], a3 = ac[cb + 3];
    // carry entering chunk j: combine chunkEnd of chunks 0..j-1 (L2-hot)
    float2 aL0 = aLp[cb], aL1 = aLp[cb + 1], aL2 = aLp[cb + 2], aL3 = aLp[cb + 3];
    float2 k0 = make_float2(0, 0), k1 = k0, k2 = k0, k3 = k0;
    for (int jj = 0; jj < j; ++jj) {
        size_t eb = (size_t)jj * NCH + b * (DM * RR) + cb;
        float2 e0 = chunkEnd[eb],     e1 = chunkEnd[eb + 1];
        float2 e2 = chunkEnd[eb + 2], e3 = chunkEnd[eb + 3];
        float nr, ni;
        nr = aL0.x * k0.x - aL0.y * k0.y + e0.x; ni = aL0.x * k0.y + aL0.y * k0.x + e0.y; k0 = make_float2(nr, ni);
        nr = aL1.x * k1.x - aL1.y * k1.y + e1.x; ni = aL1.x * k1.y + aL1.y * k1.x + e1.y; k1 = make_float2(nr, ni);
        nr = aL2.x * k2.x - aL2.y * k2.y + e2.x; ni = aL2.x * k2.y + aL2.y * k2.x + e2.y; k2 = make_float2(nr, ni);
        nr = aL3.x * k3.x - aL3.y * k3.y + e3.x; ni = aL3.x * k3.y + aL3.y * k3.x + e3.y; k3 = make_float2(nr, ni);
    }
    // q_r = c_r * carry_r * a_r^(i+1), iterated
    float2 q0 = cmul(cmul(cc[cb],     k0), a0);
    float2 q1 = cmul(cmul(cc[cb + 1], k1), a1);
    float2 q2 = cmul(cmul(cc[cb + 2], k2), a2);
    float2 q3 = cmul(cmul(cc[cb + 3], k3), a3);
    size_t base = ((size_t)(b * TT + j * CHUNK)) * DM + d;
    #pragma unroll 4
    for (int i = 0; i < CHUNK; ++i) {
        float yv = y_local[base + (size_t)i * DM] + q0.x + q1.x + q2.x + q3.x;
        y[base + (size_t)i * DM] = __float2bfloat16(yv);
        q0 = cmul(q0, a0); q1 = cmul(q1, a1);
        q2 = cmul(q2, a2); q3 = cmul(q3, a3);
    }
}

// ---------- launch ----------
extern "C" void kernel_launch(void* const* d_in, const int* in_sizes, int n_in,
                              void* d_out, int out_size, void* d_ws,
                              size_t ws_size, hipStream_t stream) {
    const float* x      = (const float*)d_in[0];
    const float* norm_w = (const float*)d_in[1];
    const float* W_in   = (const float*)d_in[2];
    const float* W_out  = (const float*)d_in[3];
    const float* a_p    = (const float*)d_in[4];
    const float* b_p    = (const float*)d_in[5];
    const float* c_p    = (const float*)d_in[6];
    float* out = (float*)d_out;

    char* ws = (char*)d_ws;
    size_t off = 0;
    auto alloc = [&](size_t bytes) {
        void* p = ws + off;
        off += (bytes + 255) & ~(size_t)255;
        return p;
    };
    __hip_bfloat16* Win_bf  = (__hip_bfloat16*)alloc((size_t)NFEAT * DM * 2);
    __hip_bfloat16* Wout_bf = (__hip_bfloat16*)alloc((size_t)DM * DM * 2);
    __hip_bfloat16* xn      = (__hip_bfloat16*)alloc((size_t)M_TOK * DM * 2);
    __hip_bfloat16* u       = (__hip_bfloat16*)alloc((size_t)M_TOK * NFEAT * 2);
    float*          y_local = (float*)alloc((size_t)M_TOK * DM * 4);
    __hip_bfloat16* y       = (__hip_bfloat16*)alloc((size_t)M_TOK * DM * 2);
    float2* ac = (float2*)alloc((size_t)DM * RR * 8);
    float2* bc = (float2*)alloc((size_t)DM * RR * 8);
    float2* cc = (float2*)alloc((size_t)DM * RR * 8);
    float2* aL = (float2*)alloc((size_t)DM * RR * 8);
    float2* chunkEnd = (float2*)alloc((size_t)NCHUNK * NCH * 8);

    // 1. fused prep (weight casts + coeffs) + RMSNorm
    {
        int cast_blocks = ((NFEAT * DM + DM * DM) / 4 + 255) / 256;
        prep_rms<<<M_TOK + cast_blocks, 256, 0, stream>>>(
            x, norm_w, W_in, W_out, a_p, b_p, c_p,
            xn, Win_bf, Wout_bf, ac, bc, cc, aL);
    }
    // 2. in_proj GEMM: u[4096,6144] = xn @ W_in^T   (256x128 tiles, 768 blks)
    gemm_in_bigm<<<dim3(NFEAT / 128, M_TOK / 256), 256, 0, stream>>>(
        xn, Win_bf, u, DM);
    // 3. chunk-local scans: u -> y_local + chunkEnd (u read once)
    scan_local<<<dim3(BATCH * DM / 256, NCHUNK), 256, 0, stream>>>(
        (const uint4*)u, ac, bc, cc, y_local, chunkEnd);
    // 4. correction: y = y_local + carry term (bf16)
    scan_fix<<<dim3(BATCH * DM / 256, NCHUNK), 256, 0, stream>>>(
        y_local, ac, cc, aL, chunkEnd, y);
    // 5. out_proj GEMM
    gemm_out<<<dim3(DM / 64, M_TOK / 64), 256, 0, stream>>>(
        y, Wout_bf, out, DM);
}

// Round 11
// 190.048 us; speedup vs baseline: 1.1434x; 1.1434x over previous
//
#include <hip/hip_runtime.h>
#include <hip/hip_bf16.h>
#include <stdint.h>

// Problem constants
#define BATCH 2
#define TT 2048
#define DM 768
#define RR 4
#define M_TOK 4096          // B*T tokens
#define NFEAT 6144          // D*R*2
#define NCH 6144            // B*D*R channels
#define CHUNK 64            // scan chunk length
#define NCHUNK 32           // T / CHUNK

typedef __attribute__((ext_vector_type(8))) short short8;
typedef __attribute__((ext_vector_type(4))) float float4v;

// ---------- helpers ----------
__device__ inline float bf2f(uint32_t bits16) {
    union { uint32_t u; float f; } x; x.u = bits16 << 16; return x.f;
}

typedef const __attribute__((address_space(1))) void* gptr_t;
typedef __attribute__((address_space(3))) void* lptr_t;

__device__ inline void async_ld16(const void* g, void* l) {
    __builtin_amdgcn_global_load_lds((gptr_t)(uintptr_t)g, (lptr_t)(uintptr_t)l,
                                     16, 0, 0);
}

__device__ inline void store_c(__hip_bfloat16* C, size_t idx, float v) {
    C[idx] = __float2bfloat16(v);
}
__device__ inline void store_c(float* C, size_t idx, float v) { C[idx] = v; }

__device__ inline uint2 pack4bf(float a, float b, float c, float d) {
    union { __hip_bfloat16 h[4]; uint2 u; } o;
    o.h[0] = __float2bfloat16(a); o.h[1] = __float2bfloat16(b);
    o.h[2] = __float2bfloat16(c); o.h[3] = __float2bfloat16(d);
    return o.u;
}

__device__ inline float2 cmul(float2 a, float2 b) {
    return make_float2(a.x * b.x - a.y * b.y, a.x * b.y + a.y * b.x);
}

// ---------- complex recurrence step: s = a*s + b*u ----------
__device__ inline void cstep(float& sr, float& si, float2 a, float2 bb,
                             uint32_t uw) {
    float ur = bf2f(uw & 0xffffu), ui = bf2f(uw >> 16);
    float tr = bb.x * ur - bb.y * ui;
    float ti = bb.x * ui + bb.y * ur;
    float nr = a.x * sr - a.y * si + tr;
    float ni = a.x * si + a.y * sr + ti;
    sr = nr; si = ni;
}

// ---------- fused prep + rmsnorm: block-role split ----------
__global__ __launch_bounds__(256) void prep_rms(
    const float* __restrict__ x, const float* __restrict__ w,
    const float* __restrict__ W_in, const float* __restrict__ W_out,
    const float* __restrict__ ap, const float* __restrict__ bp,
    const float* __restrict__ cp,
    __hip_bfloat16* __restrict__ xn,
    __hip_bfloat16* __restrict__ Win_bf, __hip_bfloat16* __restrict__ Wout_bf,
    float2* __restrict__ ac, float2* __restrict__ bc,
    float2* __restrict__ cc, float2* __restrict__ aL) {
    int bid = blockIdx.x;
    int tid = threadIdx.x;
    if (bid < M_TOK) {
        // ---- RMSNorm for token `bid` ----
        __shared__ float wsum[3];
        float4 v = make_float4(0.f, 0.f, 0.f, 0.f);
        if (tid < 192) v = ((const float4*)(x + (size_t)bid * DM))[tid];
        float ss = v.x * v.x + v.y * v.y + v.z * v.z + v.w * v.w;
        #pragma unroll
        for (int o = 1; o < 64; o <<= 1) ss += __shfl_xor(ss, o);
        if (tid < 192 && (tid & 63) == 0) wsum[tid >> 6] = ss;
        __syncthreads();
        if (tid < 192) {
            float tot = wsum[0] + wsum[1] + wsum[2];
            float scale = rsqrtf(tot * (1.f / DM) + 1e-6f);
            float4 wv = ((const float4*)w)[tid];
            ((uint2*)(xn + (size_t)bid * DM))[tid] =
                pack4bf(v.x * scale * wv.x, v.y * scale * wv.y,
                        v.z * scale * wv.z, v.w * scale * wv.w);
        }
        return;
    }
    const int N1 = NFEAT * DM / 4;   // float4 count
    const int N2 = DM * DM / 4;
    int i = (bid - M_TOK) * 256 + tid;
    if (i < N1) {
        float4 v = ((const float4*)W_in)[i];
        ((uint2*)Win_bf)[i] = pack4bf(v.x, v.y, v.z, v.w);
    } else if (i < N1 + N2) {
        int k = i - N1;
        float4 v = ((const float4*)W_out)[k];
        ((uint2*)Wout_bf)[k] = pack4bf(v.x, v.y, v.z, v.w);
    }
    if (i < DM * RR) {
        float ar = tanhf(ap[2 * i])     * 0.97f;
        float ai = tanhf(ap[2 * i + 1]) * 0.97f;
        ac[i] = make_float2(ar, ai);
        bc[i] = make_float2(tanhf(bp[2 * i]), tanhf(bp[2 * i + 1]));
        cc[i] = make_float2(tanhf(cp[2 * i]), tanhf(cp[2 * i + 1]));
        float xr = ar, xi = ai;   // a^CHUNK via 6 squarings
        #pragma unroll
        for (int k = 0; k < 6; ++k) {
            float nr = xr * xr - xi * xi;
            float ni = 2.f * xr * xi;
            xr = nr; xi = ni;
        }
        aL[i] = make_float2(xr, xi);
    }
}

// ---------- GEMM body: C[M,*] = A[M,K] * B[N,K]^T  (bf16 in, OutT out) -----
// BM x BN block tile, BK-deep LDS stage, 4 waves in 2x2, 16x16x32 bf16 MFMA,
// global_load_lds width 16, XOR-swizzled LDS (16B chunks, ^= row & (CPR-1)).
// 128x128/BK=64 measured optimal (R4: 53.8us, 719 TF); 256x128 regressed
// (R10: 78.5us, occupancy 24.6->10.5%) — occupancy beats barrier-amortization.
template <int BM, int BN, int BK, typename OutT>
__device__ inline void gemm_body(
    const __hip_bfloat16* __restrict__ A, const __hip_bfloat16* __restrict__ B,
    OutT* __restrict__ C, int K, int ldc) {
    constexpr int MI = BM / 32;
    constexpr int NJ = BN / 32;
    constexpr int CPR = BK / 8;           // 16B chunks per row
    __shared__ __attribute__((aligned(16))) __hip_bfloat16 lA[BM * BK];
    __shared__ __attribute__((aligned(16))) __hip_bfloat16 lB[BN * BK];
    const int tid  = threadIdx.x;
    const int lane = tid & 63;
    const int wave = tid >> 6;
    const int quad = lane >> 4;
    const int l15  = lane & 15;
    const int wm = (wave >> 1) * (BM / 2);
    const int wn = (wave & 1) * (BN / 2);
    const int m0 = blockIdx.y * BM;
    const int n0 = blockIdx.x * BN;

    float4v acc[MI][NJ] = {};

    for (int k0 = 0; k0 < K; k0 += BK) {
        __syncthreads();
        #pragma unroll
        for (int it = 0; it < BM * CPR / 256; ++it) {
            int p = it * 256 + tid;
            int row = p / CPR;
            int cg = (p & (CPR - 1)) ^ (row & (CPR - 1));
            async_ld16(A + (size_t)(m0 + row) * K + k0 + cg * 8, lA + p * 8);
        }
        #pragma unroll
        for (int it = 0; it < BN * CPR / 256; ++it) {
            int p = it * 256 + tid;
            int row = p / CPR;
            int cg = (p & (CPR - 1)) ^ (row & (CPR - 1));
            async_ld16(B + (size_t)(n0 + row) * K + k0 + cg * 8, lB + p * 8);
        }
        __syncthreads();
        #pragma unroll
        for (int s = 0; s < BK / 32; ++s) {
            short8 af[MI], bfr[NJ];
            #pragma unroll
            for (int i = 0; i < MI; ++i) {
                int r = wm + i * 16 + l15;
                int c = (s * 4 + quad) ^ (r & (CPR - 1));
                af[i] = *(const short8*)(lA + r * BK + c * 8);
            }
            #pragma unroll
            for (int j = 0; j < NJ; ++j) {
                int r = wn + j * 16 + l15;
                int c = (s * 4 + quad) ^ (r & (CPR - 1));
                bfr[j] = *(const short8*)(lB + r * BK + c * 8);
            }
            #pragma unroll
            for (int i = 0; i < MI; ++i)
                #pragma unroll
                for (int j = 0; j < NJ; ++j)
                    acc[i][j] = __builtin_amdgcn_mfma_f32_16x16x32_bf16(
                        af[i], bfr[j], acc[i][j], 0, 0, 0);
        }
    }
    // epilogue: C/D layout col = lane&15, row = quad*4 + reg (m89-verified)
    #pragma unroll
    for (int i = 0; i < MI; ++i)
        #pragma unroll
        for (int j = 0; j < NJ; ++j)
            #pragma unroll
            for (int rg = 0; rg < 4; ++rg) {
                int row = m0 + wm + i * 16 + quad * 4 + rg;
                int col = n0 + wn + j * 16 + l15;
                store_c(C, (size_t)row * ldc + col, acc[i][j][rg]);
            }
}

__global__ __launch_bounds__(256) void gemm_in(
    const __hip_bfloat16* __restrict__ A, const __hip_bfloat16* __restrict__ B,
    __hip_bfloat16* __restrict__ C, int K) {
    gemm_body<128, 128, 64, __hip_bfloat16>(A, B, C, K, NFEAT);
}

__global__ __launch_bounds__(256) void gemm_out(
    const __hip_bfloat16* __restrict__ A, const __hip_bfloat16* __restrict__ B,
    float* __restrict__ C, int K) {
    gemm_body<64, 64, 128, float>(A, B, C, K, DM);
}

// ---------- scan_local: chunk-local scans; emit y_local (bf16) + chunkEnd --
// One thread per (batch,d): 4 channels via uint4; u read ONCE.
__global__ __launch_bounds__(256) void scan_local(
    const uint4* __restrict__ u4,              // [(b*T+t)*768 + d]
    const float2* __restrict__ ac, const float2* __restrict__ bc,
    const float2* __restrict__ cc,
    __hip_bfloat16* __restrict__ y_local,      // [M_TOK][DM] bf16
    float2* __restrict__ chunkEnd) {           // [NCHUNK][NCH]
    int g = blockIdx.x * 256 + threadIdx.x;    // 0..1535
    int j = blockIdx.y;
    int b = g >= DM;
    int d = g - b * DM;
    int cb = d * RR;
    float2 a0 = ac[cb], a1 = ac[cb + 1], a2 = ac[cb + 2], a3 = ac[cb + 3];
    float2 b0 = bc[cb], b1 = bc[cb + 1], b2 = bc[cb + 2], b3 = bc[cb + 3];
    float2 c0 = cc[cb], c1 = cc[cb + 1], c2 = cc[cb + 2], c3 = cc[cb + 3];
    float s0r = 0, s0i = 0, s1r = 0, s1i = 0;
    float s2r = 0, s2i = 0, s3r = 0, s3i = 0;
    size_t base = ((size_t)(b * TT + j * CHUNK)) * DM + d;
    #pragma unroll 4
    for (int i = 0; i < CHUNK; ++i) {
        uint4 uw = u4[base + (size_t)i * DM];
        cstep(s0r, s0i, a0, b0, uw.x);
        cstep(s1r, s1i, a1, b1, uw.y);
        cstep(s2r, s2i, a2, b2, uw.z);
        cstep(s3r, s3i, a3, b3, uw.w);
        float yv = c0.x * s0r - c0.y * s0i + c1.x * s1r - c1.y * s1i
                 + c2.x * s2r - c2.y * s2i + c3.x * s3r - c3.y * s3i;
        y_local[base + (size_t)i * DM] = __float2bfloat16(yv);
    }
    size_t eb = (size_t)j * NCH + b * (DM * RR) + cb;
    chunkEnd[eb]     = make_float2(s0r, s0i);
    chunkEnd[eb + 1] = make_float2(s1r, s1i);
    chunkEnd[eb + 2] = make_float2(s2r, s2i);
    chunkEnd[eb + 3] = make_float2(s3r, s3i);
}

// ---------- scan_fix: carry combine + closed-form correction ----------
// y[t][d] = y_local[t][d] + sum_r Re( c_r * a_r^(i+1) * carry_r )
__global__ __launch_bounds__(256) void scan_fix(
    const __hip_bfloat16* __restrict__ y_local,
    const float2* __restrict__ ac, const float2* __restrict__ cc,
    const float2* __restrict__ aLp, const float2* __restrict__ chunkEnd,
    __hip_bfloat16* __restrict__ y) {          // [B*T*D]
    int g = blockIdx.x * 256 + threadIdx.x;    // 0..1535
    int j = blockIdx.y;
    int b = g >= DM;
    int d = g - b * DM;
    int cb = d * RR;
    float2 a0 = ac[cb], a1 = ac[cb + 1], a2 = ac[cb + 2], a3 = ac[cb + 3];
    // carry entering chunk j: combine chunkEnd of chunks 0..j-1 (L2-hot)
    float2 aL0 = aLp[cb], aL1 = aLp[cb + 1], aL2 = aLp[cb + 2], aL3 = aLp[cb + 3];
    float2 k0 = make_float2(0, 0), k1 = k0, k2 = k0, k3 = k0;
    for (int jj = 0; jj < j; ++jj) {
        size_t eb = (size_t)jj * NCH + b * (DM * RR) + cb;
        float2 e0 = chunkEnd[eb],     e1 = chunkEnd[eb + 1];
        float2 e2 = chunkEnd[eb + 2], e3 = chunkEnd[eb + 3];
        float nr, ni;
        nr = aL0.x * k0.x - aL0.y * k0.y + e0.x; ni = aL0.x * k0.y + aL0.y * k0.x + e0.y; k0 = make_float2(nr, ni);
        nr = aL1.x * k1.x - aL1.y * k1.y + e1.x; ni = aL1.x * k1.y + aL1.y * k1.x + e1.y; k1 = make_float2(nr, ni);
        nr = aL2.x * k2.x - aL2.y * k2.y + e2.x; ni = aL2.x * k2.y + aL2.y * k2.x + e2.y; k2 = make_float2(nr, ni);
        nr = aL3.x * k3.x - aL3.y * k3.y + e3.x; ni = aL3.x * k3.y + aL3.y * k3.x + e3.y; k3 = make_float2(nr, ni);
    }
    // q_r = c_r * carry_r * a_r^(i+1), iterated
    float2 q0 = cmul(cmul(cc[cb],     k0), a0);
    float2 q1 = cmul(cmul(cc[cb + 1], k1), a1);
    float2 q2 = cmul(cmul(cc[cb + 2], k2), a2);
    float2 q3 = cmul(cmul(cc[cb + 3], k3), a3);
    size_t base = ((size_t)(b * TT + j * CHUNK)) * DM + d;
    #pragma unroll 4
    for (int i = 0; i < CHUNK; ++i) {
        float yv = bf2f(((const uint16_t*)y_local)[base + (size_t)i * DM])
                 + q0.x + q1.x + q2.x + q3.x;
        y[base + (size_t)i * DM] = __float2bfloat16(yv);
        q0 = cmul(q0, a0); q1 = cmul(q1, a1);
        q2 = cmul(q2, a2); q3 = cmul(q3, a3);
    }
}

// ---------- launch ----------
extern "C" void kernel_launch(void* const* d_in, const int* in_sizes, int n_in,
                              void* d_out, int out_size, void* d_ws,
                              size_t ws_size, hipStream_t stream) {
    const float* x      = (const float*)d_in[0];
    const float* norm_w = (const float*)d_in[1];
    const float* W_in   = (const float*)d_in[2];
    const float* W_out  = (const float*)d_in[3];
    const float* a_p    = (const float*)d_in[4];
    const float* b_p    = (const float*)d_in[5];
    const float* c_p    = (const float*)d_in[6];
    float* out = (float*)d_out;

    char* ws = (char*)d_ws;
    size_t off = 0;
    auto alloc = [&](size_t bytes) {
        void* p = ws + off;
        off += (bytes + 255) & ~(size_t)255;
        return p;
    };
    __hip_bfloat16* Win_bf  = (__hip_bfloat16*)alloc((size_t)NFEAT * DM * 2);
    __hip_bfloat16* Wout_bf = (__hip_bfloat16*)alloc((size_t)DM * DM * 2);
    __hip_bfloat16* xn      = (__hip_bfloat16*)alloc((size_t)M_TOK * DM * 2);
    __hip_bfloat16* u       = (__hip_bfloat16*)alloc((size_t)M_TOK * NFEAT * 2);
    __hip_bfloat16* y_local = (__hip_bfloat16*)alloc((size_t)M_TOK * DM * 2);
    __hip_bfloat16* y       = (__hip_bfloat16*)alloc((size_t)M_TOK * DM * 2);
    float2* ac = (float2*)alloc((size_t)DM * RR * 8);
    float2* bc = (float2*)alloc((size_t)DM * RR * 8);
    float2* cc = (float2*)alloc((size_t)DM * RR * 8);
    float2* aL = (float2*)alloc((size_t)DM * RR * 8);
    float2* chunkEnd = (float2*)alloc((size_t)NCHUNK * NCH * 8);

    // 1. fused prep (weight casts + coeffs) + RMSNorm
    {
        int cast_blocks = ((NFEAT * DM + DM * DM) / 4 + 255) / 256;
        prep_rms<<<M_TOK + cast_blocks, 256, 0, stream>>>(
            x, norm_w, W_in, W_out, a_p, b_p, c_p,
            xn, Win_bf, Wout_bf, ac, bc, cc, aL);
    }
    // 2. in_proj GEMM: u[4096,6144] = xn @ W_in^T   (128x128, BK=64)
    gemm_in<<<dim3(NFEAT / 128, M_TOK / 128), 256, 0, stream>>>(
        xn, Win_bf, u, DM);
    // 3. chunk-local scans: u -> y_local (bf16) + chunkEnd (u read once)
    scan_local<<<dim3(BATCH * DM / 256, NCHUNK), 256, 0, stream>>>(
        (const uint4*)u, ac, bc, cc, y_local, chunkEnd);
    // 4. correction: y = y_local + carry term (bf16)
    scan_fix<<<dim3(BATCH * DM / 256, NCHUNK), 256, 0, stream>>>(
        y_local, ac, cc, aL, chunkEnd, y);
    // 5. out_proj GEMM
    gemm_out<<<dim3(DM / 64, M_TOK / 64), 256, 0, stream>>>(
        y, Wout_bf, out, DM);
}